// Round 1
// baseline (154.351 us; speedup 1.0000x reference)
//
#include <hip/hip_runtime.h>
#include <hip/hip_bf16.h>

// ---------------------------------------------------------------------------
// UpThreeOffsetsConvShareWeights: algebraic restructuring.
//
// Key identities:
//  * OFFSET0[t] == (1-kz, 1-ky, 1-kx)  => deform offsets contract the kernel
//    grid per-dimension: tap samples at (k-1)(1-alpha). Fully separable.
//    1D collapse matrix T_a over offsets {-1,0,1}:
//      T[0]=[1-a, a, 0], T[1]=[0,1,0], T[2]=[0, a, 1-a]
//  * upsample x2 (nearest) + 3x3x3 conv == per output phase (a,b,c) in {0,1}^3
//    a 2x2x2-tap conv on the ORIGINAL 32^3 grid:
//      U[a=0][k] = [T[k][-1], T[k][0]+T[k][+1]]   (input offsets -1, 0)
//      U[a=1][k] = [T[k][-1]+T[k][0], T[k][+1]]   (input offsets  0, +1)
//  * BN1 folds into weights/bias; combine conv + BN2 folds likewise.
//
// => per phase: GEMM  M=32768 (32^3 spatial) x N=96 (3 br x 32 ch) x K=512
//    (64 ch x 8 taps), then fused K=96 combine GEMM. 2.7e10 FLOP total, bf16
//    MFMA 32x32x16.
// ---------------------------------------------------------------------------

typedef __bf16 bf16x8 __attribute__((ext_vector_type(8)));
typedef float f32x16 __attribute__((ext_vector_type(16)));

__device__ inline unsigned short f2bf(float f) {
  unsigned int u = __float_as_uint(f);
  u += 0x7FFFu + ((u >> 16) & 1u);
  return (unsigned short)(u >> 16);
}

__device__ inline bf16x8 bc16(uint4 v) { return __builtin_bit_cast(bf16x8, v); }

// ---------------- K0: transpose x [64][32768] f32 -> xT [32768][64] bf16 ----
__global__ void k_transpose(const float* __restrict__ x,
                            unsigned short* __restrict__ xT) {
  __shared__ unsigned short t[64][65];
  int s0 = blockIdx.x * 64;
  int lane = threadIdx.x & 63;
  int grp = threadIdx.x >> 6;
#pragma unroll
  for (int c = grp; c < 64; c += 4)
    t[c][lane] = f2bf(x[c * 32768 + s0 + lane]);
  __syncthreads();
#pragma unroll
  for (int s = grp; s < 64; s += 4)
    xT[(size_t)(s0 + s) * 64 + lane] = t[lane][s];
}

// ---------------- K1: build phase-collapsed, BN1-folded, MFMA-swizzled B ----
// W_sw layout (ushort): e = ((p*32 + s)*3 + nt)*512 + lane*8 + j
//   value = B[kk = 16 s + 8*(lane>>5) + j][n = nt*32 + (lane&31)]
//   kk = tap*64 + ch  (tap = jz*4+jy*2+jx in {0..7}, ch in [0,64))
__device__ inline float ucoef(int abit, int k, int jbit, float alpha) {
  if (abit == 0) return (k == 0) ? (jbit ? alpha : 1.f - alpha) : (jbit ? 1.f : 0.f);
  return (k == 2) ? (jbit ? 1.f - alpha : alpha) : (jbit ? 0.f : 1.f);
}

__global__ void k_weights(const float* __restrict__ w_def,
                          const float* __restrict__ bn1_g,
                          const float* __restrict__ bn1_v,
                          unsigned short* __restrict__ W_sw) {
  int e = blockIdx.x * 256 + threadIdx.x;  // < 393216
  int j = e & 7;
  int lane = (e >> 3) & 63;
  int idx = e >> 9;
  int nt = idx % 3;
  idx /= 3;
  int s = idx & 31;
  int p = idx >> 5;
  int o = lane & 31;
  int br = nt;  // n = nt*32 + o => branch == nt
  int kk = 16 * s + ((lane >> 5) << 3) + j;
  int tap = kk >> 6, ch = kk & 63;
  int jz = (tap >> 2) & 1, jy = (tap >> 1) & 1, jx = tap & 1;
  int a = (p >> 2) & 1, b = (p >> 1) & 1, cp = p & 1;
  float alpha = (br == 0) ? 0.f : ((br == 1) ? 0.4f : 0.7f);
  const float* wb = w_def + (o * 64 + ch) * 27;
  float sum = 0.f;
  for (int kz = 0; kz < 3; ++kz) {
    float uz = ucoef(a, kz, jz, alpha);
    if (uz == 0.f) continue;
    for (int ky = 0; ky < 3; ++ky) {
      float uy = ucoef(b, ky, jy, alpha);
      if (uy == 0.f) continue;
      float uzy = uz * uy;
      for (int kx = 0; kx < 3; ++kx) {
        float ux = ucoef(cp, kx, jx, alpha);
        if (ux != 0.f) sum += wb[kz * 9 + ky * 3 + kx] * uzy * ux;
      }
    }
  }
  float s1 = bn1_g[o] * rsqrtf(bn1_v[o] + 1e-5f);
  W_sw[e] = f2bf(sum * s1);
}

// ---------------- K2b: combine-weight fragments + folded biases -------------
// W2_sw (ushort): e = (s2*64 + lane)*8 + j
//   value = B2[k = 16 s2 + 8*(lane>>5) + j][n = lane&31] = w_comb[n][k]*scale2[n]
__global__ void k_small(const float* __restrict__ w_comb,
                        const float* __restrict__ b_comb,
                        const float* __restrict__ bn2_g,
                        const float* __restrict__ bn2_b,
                        const float* __restrict__ bn2_m,
                        const float* __restrict__ bn2_v,
                        const float* __restrict__ b_def,
                        const float* __restrict__ bn1_g,
                        const float* __restrict__ bn1_b,
                        const float* __restrict__ bn1_m,
                        const float* __restrict__ bn1_v,
                        unsigned short* __restrict__ W2_sw,
                        float* __restrict__ bias1,
                        float* __restrict__ bias2) {
  int tid = threadIdx.x;
  for (int e = tid; e < 3072; e += 256) {
    int j = e & 7;
    int lane = (e >> 3) & 63;
    int s2 = e >> 9;
    int n = lane & 31;
    int k = 16 * s2 + ((lane >> 5) << 3) + j;
    float sc2 = bn2_g[n] * rsqrtf(bn2_v[n] + 1e-5f);
    W2_sw[e] = f2bf(w_comb[n * 96 + k] * sc2);
  }
  if (tid < 32) {
    float s1 = bn1_g[tid] * rsqrtf(bn1_v[tid] + 1e-5f);
    bias1[tid] = (b_def[tid] - bn1_m[tid]) * s1 + bn1_b[tid];
    float s2 = bn2_g[tid] * rsqrtf(bn2_v[tid] + 1e-5f);
    bias2[tid] = (b_comb[tid] - bn2_m[tid]) * s2 + bn2_b[tid];
  }
}

// ---------------- K2: main fused kernel -------------------------------------
// Grid 512 blocks, 256 thr (4 waves). Block tile: 4(z) x 2(y) x 8(x) input
// positions -> 8x4x16 output region x 32 ch, all 8 phases (2 per wave).
// LDS x-tile [6][4][10][64] bf16 with channel rotation (c + 8*row) & 63 for
// bank spread; actT per-wave 32x104 bf16 for C->A relayout of the combine.
__launch_bounds__(256, 2)
__global__ void k_main(const unsigned short* __restrict__ xT,
                       const unsigned short* __restrict__ W_sw,
                       const unsigned short* __restrict__ W2_sw,
                       const float* __restrict__ bias1f,
                       const float* __restrict__ bias2f,
                       float* __restrict__ out) {
  __shared__ unsigned short xt[15360];        // 6*4*10*64
  __shared__ unsigned short actT[4][32 * 104];
  int tid = threadIdx.x;
  int lane = tid & 63;
  int wv = tid >> 6;
  int bid = blockIdx.x;
  int tx = bid & 3, ty = (bid >> 2) & 15, tz = bid >> 6;
  int i0 = tz * 4, j0 = ty * 2, k0 = tx * 8;

  // stage x tile (halo 1, zero-padded)
  for (int t = tid; t < 1920; t += 256) {
    int cblk = t & 7;
    int r = t >> 3;                    // row = (z*4+y)*10 + x
    int xx = r % 10;
    int zy = r / 10;
    int yy = zy & 3;
    int zz = zy >> 2;
    int gz = i0 + zz - 1, gy = j0 + yy - 1, gx = k0 + xx - 1;
    uint4 v = make_uint4(0u, 0u, 0u, 0u);
    if ((unsigned)gz < 32u && (unsigned)gy < 32u && (unsigned)gx < 32u)
      v = *(const uint4*)(xT + ((((gz * 32 + gy) * 32 + gx) << 6) + (cblk << 3)));
    *(uint4*)(xt + ((r << 6) + (((cblk + r) << 3) & 63))) = v;
  }

  bf16x8 b2f[6];
  const uint4* w2q = (const uint4*)W2_sw;
#pragma unroll
  for (int s2 = 0; s2 < 6; ++s2) b2f[s2] = bc16(w2q[s2 * 64 + lane]);
  float bias1 = bias1f[lane & 31];
  float bias2 = bias2f[lane & 31];
  __syncthreads();

  int h = lane >> 5;
  int h8 = h << 3;
  int ax = lane & 7, ay = (lane >> 3) & 1, az = (lane >> 4) & 1;
  const uint4* wq = (const uint4*)W_sw;

  for (int pp = 0; pp < 2; ++pp) {
    int p = wv + pp * 4;  // wave handles phases wv and wv+4
    int a = (p >> 2) & 1, bph = (p >> 1) & 1, cp = p & 1;
    int base = ((az + a) * 4 + (ay + bph)) * 10 + (ax + cp);
    f32x16 acc[2][3];
#pragma unroll
    for (int mt = 0; mt < 2; ++mt)
#pragma unroll
      for (int nt = 0; nt < 3; ++nt) acc[mt][nt] = (f32x16)0.f;

    const uint4* wph = wq + p * 6144;
#pragma unroll 8
    for (int s = 0; s < 32; ++s) {
      int tap = s >> 2;
      int row0 = base + (tap >> 2) * 40 + ((tap >> 1) & 1) * 10 + (tap & 1);
      int row1 = row0 + 80;  // mt=1: z += 2
      int c0 = ((s & 3) << 4) + h8;
      int e0 = (row0 << 6) + ((c0 + (row0 << 3)) & 63);
      int e1 = (row1 << 6) + ((c0 + (row1 << 3)) & 63);
      bf16x8 a0 = bc16(*(const uint4*)(xt + e0));
      bf16x8 a1 = bc16(*(const uint4*)(xt + e1));
      const uint4* wf = wph + s * 192 + lane;
      bf16x8 bb0 = bc16(wf[0]);
      bf16x8 bb1 = bc16(wf[64]);
      bf16x8 bb2 = bc16(wf[128]);
      acc[0][0] = __builtin_amdgcn_mfma_f32_32x32x16_bf16(a0, bb0, acc[0][0], 0, 0, 0);
      acc[1][0] = __builtin_amdgcn_mfma_f32_32x32x16_bf16(a1, bb0, acc[1][0], 0, 0, 0);
      acc[0][1] = __builtin_amdgcn_mfma_f32_32x32x16_bf16(a0, bb1, acc[0][1], 0, 0, 0);
      acc[1][1] = __builtin_amdgcn_mfma_f32_32x32x16_bf16(a1, bb1, acc[1][1], 0, 0, 0);
      acc[0][2] = __builtin_amdgcn_mfma_f32_32x32x16_bf16(a0, bb2, acc[0][2], 0, 0, 0);
      acc[1][2] = __builtin_amdgcn_mfma_f32_32x32x16_bf16(a1, bb2, acc[1][2], 0, 0, 0);
    }

    unsigned short* aw = actT[wv];
    int o2 = lane & 31;
#pragma unroll
    for (int mt = 0; mt < 2; ++mt) {
      // BN1+ReLU, C-layout -> act matrix [m][n] in LDS (bf16)
#pragma unroll
      for (int nt = 0; nt < 3; ++nt) {
#pragma unroll
        for (int r = 0; r < 16; ++r) {
          int m = (r & 3) + ((r >> 2) << 3) + (h << 2);
          float v = fmaxf(acc[mt][nt][r] + bias1, 0.f);
          aw[m * 104 + nt * 32 + o2] = f2bf(v);
        }
      }
      // fused combine GEMM (K=96) + BN2 + ReLU
      f32x16 acc2 = (f32x16)0.f;
#pragma unroll
      for (int s2 = 0; s2 < 6; ++s2) {
        bf16x8 a2 = bc16(*(const uint4*)(aw + (o2 * 104 + (s2 << 4) + h8)));
        acc2 = __builtin_amdgcn_mfma_f32_32x32x16_bf16(a2, b2f[s2], acc2, 0, 0, 0);
      }
      float* ob = out + (size_t)o2 * 262144;
#pragma unroll
      for (int r = 0; r < 16; ++r) {
        int m = (r & 3) + ((r >> 2) << 3) + (h << 2);
        int dz = 2 * mt + (m >> 4), dy = (m >> 3) & 1, dx = m & 7;
        int Z = 2 * (i0 + dz) + a, Y = 2 * (j0 + dy) + bph, X = 2 * (k0 + dx) + cp;
        ob[(Z << 12) + (Y << 6) + X] = fmaxf(acc2[r] + bias2, 0.f);
      }
    }
  }
}

// ---------------------------------------------------------------------------
extern "C" void kernel_launch(void* const* d_in, const int* in_sizes, int n_in,
                              void* d_out, int out_size, void* d_ws, size_t ws_size,
                              hipStream_t stream) {
  (void)in_sizes; (void)n_in; (void)out_size; (void)ws_size;
  const float* x      = (const float*)d_in[0];
  const float* w_def  = (const float*)d_in[1];
  const float* b_def  = (const float*)d_in[2];
  const float* bn1_g  = (const float*)d_in[3];
  const float* bn1_b  = (const float*)d_in[4];
  const float* bn1_m  = (const float*)d_in[5];
  const float* bn1_v  = (const float*)d_in[6];
  const float* w_comb = (const float*)d_in[7];
  const float* b_comb = (const float*)d_in[8];
  const float* bn2_g  = (const float*)d_in[9];
  const float* bn2_b  = (const float*)d_in[10];
  const float* bn2_m  = (const float*)d_in[11];
  const float* bn2_v  = (const float*)d_in[12];

  char* ws = (char*)d_ws;
  unsigned short* xT   = (unsigned short*)(ws);             // 4,194,304 B
  unsigned short* W_sw = (unsigned short*)(ws + 4194304);   //   786,432 B
  unsigned short* W2sw = (unsigned short*)(ws + 4980736);   //     6,144 B
  float* bias1 = (float*)(ws + 4986880);                    //       128 B
  float* bias2 = (float*)(ws + 4987008);                    //       128 B
  float* out = (float*)d_out;

  hipLaunchKernelGGL(k_transpose, dim3(512), dim3(256), 0, stream, x, xT);
  hipLaunchKernelGGL(k_weights, dim3(1536), dim3(256), 0, stream,
                     w_def, bn1_g, bn1_v, W_sw);
  hipLaunchKernelGGL(k_small, dim3(1), dim3(256), 0, stream,
                     w_comb, b_comb, bn2_g, bn2_b, bn2_m, bn2_v,
                     b_def, bn1_g, bn1_b, bn1_m, bn1_v, W2sw, bias1, bias2);
  hipLaunchKernelGGL(k_main, dim3(512), dim3(256), 0, stream,
                     xT, W_sw, W2sw, bias1, bias2, out);
}